// Round 7
// baseline (388.711 us; speedup 1.0000x reference)
//
#include <hip/hip_runtime.h>
#include <hip/hip_fp16.h>
#include <math.h>

// CrossFeatureAffinityPooling on gfx950 — R7
// R6 + NSPLIT=4 with __launch_bounds__(256,4): 1024 blocks = 4 blocks/CU
// (latency-bound core -> more antiphase overlap). Merged O kept fp16 in-place
// in Ppart[0] (no fp32 Opre pass); k_gnapply reads fp16.

typedef _Float16 v8h __attribute__((ext_vector_type(8)));
typedef _Float16 v4h __attribute__((ext_vector_type(4)));
typedef float    v4f __attribute__((ext_vector_type(4)));

#define NB 4
#define NC 256
#define NS 4096
#define NG 32
#define GEPS 1e-5f
#define NSPLIT 4
#define KSTRIDE 272            // halves per K-tile row (256 data + 16 pad)
#define KTILE   8704           // halves per 32-row K tile (17408 B)
#define PSTRIDE 40             // halves per P row (32 data + 8 pad)

// raw barrier: LDS-visibility only (lgkm drain), vmem stays in flight
#define ASYNC_BARRIER() asm volatile("s_waitcnt lgkmcnt(0)\n\ts_barrier" ::: "memory")

// DPP rotation-reduce within each 16-lane row (the l15 domain of MFMA quads)
template <int CTRL>
__device__ __forceinline__ float dpp_rot(float x) {
    int r = __builtin_amdgcn_update_dpp(__float_as_int(x), __float_as_int(x),
                                        CTRL, 0xF, 0xF, false);
    return __int_as_float(r);
}
__device__ __forceinline__ float row_max16(float x) {
    x = fmaxf(x, dpp_rot<0x128>(x));
    x = fmaxf(x, dpp_rot<0x124>(x));
    x = fmaxf(x, dpp_rot<0x122>(x));
    x = fmaxf(x, dpp_rot<0x121>(x));
    return x;
}
__device__ __forceinline__ float row_sum16(float x) {
    x = x + dpp_rot<0x128>(x);
    x = x + dpp_rot<0x124>(x);
    x = x + dpp_rot<0x122>(x);
    x = x + dpp_rot<0x121>(x);
    return x;
}

// ---------------- K0: convert weights into MFMA-frag order (W only) --------
__global__ __launch_bounds__(256) void k_convert(const float* __restrict__ Wh,
    const float* __restrict__ Wu, _Float16* __restrict__ Wh16, _Float16* __restrict__ Wu16)
{
    const int i = blockIdx.x * 256 + threadIdx.x;   // i < NC*NC
    const int o = i >> 8, c = i & 255;
    const int idx = ((((o >> 4) * 8 + (c >> 5)) * 4 + ((c >> 3) & 3)) * 16
                     + (o & 15)) * 8 + (c & 7);
    Wh16[idx] = (_Float16)Wh[i];
    Wu16[idx] = (_Float16)Wu[i];
}

// ---------------- K1: q^T / k^T GEMM (+ fused Uh materialization) ----------
__global__ __launch_bounds__(256) void k_qkgemm(const float* __restrict__ Hand,
    const float* __restrict__ U, const _Float16* __restrict__ Wh16,
    const _Float16* __restrict__ Wu16, const float* __restrict__ WHb,
    const float* __restrict__ WUb, _Float16* __restrict__ qT,
    _Float16* __restrict__ kTsw, _Float16* __restrict__ Uh)
{
    const int nt = blockIdx.x, b = blockIdx.y, z = blockIdx.z;
    const float*    X    = z ? U    : Hand;
    const _Float16* W    = z ? Wu16 : Wh16;
    const float*    bias = z ? WUb  : WHb;

    const int tid = threadIdx.x, w = tid >> 6, lane = tid & 63;
    const int q4 = lane >> 4, l15 = lane & 15;
    const int n = nt * 64 + w * 16 + l15;

    const float* Xcol = X + (size_t)b * NC * NS + n;
    v8h A[8];
#pragma unroll
    for (int kc = 0; kc < 8; ++kc) {
        const int c0 = kc * 32 + q4 * 8;
        v8h a;
#pragma unroll
        for (int j = 0; j < 8; ++j) a[j] = (_Float16)Xcol[(size_t)(c0 + j) * NS];
        A[kc] = a;
    }

    // fused: z=1 blocks hold U^T[n][c] fp16 frags -> write Uh[b][c][n]
    if (z == 1) {
        _Float16* ub = Uh + (size_t)b * NC * NS + n;
#pragma unroll
        for (int kc = 0; kc < 8; ++kc) {
            const int c0 = kc * 32 + q4 * 8;
#pragma unroll
            for (int j = 0; j < 8; ++j) ub[(size_t)(c0 + j) * NS] = A[kc][j];
        }
    }

#pragma unroll 4
    for (int osub = 0; osub < 16; ++osub) {
        const int o = osub * 16 + l15;
        v4f acc = {0.f, 0.f, 0.f, 0.f};
#pragma unroll
        for (int kc = 0; kc < 8; ++kc) {
            const v8h bf = *(const v8h*)(W + ((size_t)(osub * 8 + kc) * 64 + lane) * 8);
            acc = __builtin_amdgcn_mfma_f32_16x16x32_f16(A[kc], bf, acc, 0, 0, 0);
        }
        const float bv = bias[o];
        if (z == 0) {
            _Float16* orow = qT + ((size_t)b * NS + nt * 64 + w * 16 + q4 * 4) * NC + o;
#pragma unroll
            for (int r = 0; r < 4; ++r) orow[(size_t)r * NC] = (_Float16)(acc[r] + bv);
        } else {
            _Float16* kb = kTsw + (size_t)b * 128 * KTILE;
#pragma unroll
            for (int r = 0; r < 4; ++r) {
                const int m = nt * 64 + w * 16 + q4 * 4 + r;
                kb[(size_t)(m >> 5) * KTILE + (m & 31) * KSTRIDE + o] = (_Float16)(acc[r] + bv);
            }
        }
    }
}

// ---------------- K2: flash attention partial, software-pipelined ----------
__global__ __launch_bounds__(256, 4) void k_attn(const _Float16* __restrict__ qT,
    const _Float16* __restrict__ kTsw, const _Float16* __restrict__ Uh,
    _Float16* __restrict__ Ppart, float* __restrict__ mstat, float* __restrict__ lstat)
{
    const int b  = blockIdx.x;
    const int nt = blockIdx.y;
    const int s  = blockIdx.z;
    const int t0 = s * 32;
    const int t1 = t0 + 32;

    __shared__ __align__(16) _Float16 Klds[2][KTILE];     // 2 x 17 KiB, padded rows
    __shared__ __align__(16) _Float16 Plds[64 * PSTRIDE]; // 5 KiB, padded rows
    __shared__ __align__(16) float alphaS[64];

    const int tid = threadIdx.x, w = tid >> 6, lane = tid & 63;
    const int q4 = lane >> 4, l15 = lane & 15;

    const _Float16* kTb = kTsw + (size_t)b * 128 * KTILE;
    const _Float16* Uhb = Uh + (size_t)b * NC * NS;

    // prologue: DMA K[t0] -> buf (t0&1). 17 chunks of 1 KiB; each wave copies 5
    // via (w*5+j) mod 17 (3 chunks double-copied -> uniform per-wave vmcnt).
    {
        const _Float16* src = kTb + (size_t)t0 * KTILE;
#pragma unroll
        for (int j = 0; j < 5; ++j) {
            const int ch = (w * 5 + j) % 17;
            __builtin_amdgcn_global_load_lds(
                (const __attribute__((address_space(1))) void*)(src + ch * 512 + lane * 8),
                (__attribute__((address_space(3))) void*)(&Klds[t0 & 1][ch * 512]), 16, 0, 0);
        }
    }

    v8h Q[8];
    {
        const _Float16* qrow = qT + ((size_t)b * NS + nt * 64 + w * 16 + l15) * NC;
#pragma unroll
        for (int kc = 0; kc < 8; ++kc) Q[kc] = *(const v8h*)(qrow + kc * 32 + q4 * 8);
    }

    v4f O[4][4];
#pragma unroll
    for (int i = 0; i < 4; ++i)
#pragma unroll
        for (int j = 0; j < 4; ++j) O[i][j] = (v4f){0.f, 0.f, 0.f, 0.f};
    float mi[4] = {-INFINITY, -INFINITY, -INFINITY, -INFINITY};
    float li[4] = {0.f, 0.f, 0.f, 0.f};   // lane-local partial (own cols only)

    for (int t = t0; t < t1; ++t) {
        const int p = t & 1;
        const int m0 = t * 32;

        // ---- U[t] prefetch to VGPRs ----
        v8h Ur[4];
#pragma unroll
        for (int js = 0; js < 4; ++js)
            Ur[js] = *(const v8h*)(Uhb + (size_t)(w * 64 + js * 16 + l15) * NS + m0 + q4 * 8);
        asm volatile("" ::: "memory");   // pin U-before-DMA issue order (vmcnt math)

        // ---- DMA K[t+1] into other buffer; last iter wraps (uniform counts) ----
        {
            const int tn = (t + 1 < t1) ? t + 1 : t0;
            const _Float16* src = kTb + (size_t)tn * KTILE;
#pragma unroll
            for (int j = 0; j < 5; ++j) {
                const int ch = (w * 5 + j) % 17;
                __builtin_amdgcn_global_load_lds(
                    (const __attribute__((address_space(1))) void*)(src + ch * 512 + lane * 8),
                    (__attribute__((address_space(3))) void*)(&Klds[p ^ 1][ch * 512]), 16, 0, 0);
            }
        }

        // outstanding: DMA(t)=5 oldest, U(t)=4, DMA(t+1)=5 -> retire DMA(t) only
        asm volatile("s_waitcnt vmcnt(9)" ::: "memory");
        ASYNC_BARRIER();   // K[t] resident for all; Plds consumed by all

        // ---- QK^T: 16 n-rows x 32 m per wave ----
        v4f sv[2];
        sv[0] = (v4f){0.f, 0.f, 0.f, 0.f};
        sv[1] = (v4f){0.f, 0.f, 0.f, 0.f};
#pragma unroll
        for (int kc = 0; kc < 8; ++kc) {
#pragma unroll
            for (int ms = 0; ms < 2; ++ms) {
                const v8h kf = *(const v8h*)(&Klds[p][(ms * 16 + l15) * KSTRIDE
                                             + (kc * 4 + q4) * 8]);
                sv[ms] = __builtin_amdgcn_mfma_f32_16x16x32_f16(Q[kc], kf, sv[ms], 0, 0, 0);
            }
        }

        // ---- online softmax: DPP max (VALU pipe), lane-local li ----
        float al[4];
#pragma unroll
        for (int r = 0; r < 4; ++r) {
            const float tm = row_max16(fmaxf(sv[0][r], sv[1][r]));
            const float mn = fmaxf(mi[r], tm);
            al[r] = __expf(mi[r] - mn);
            mi[r] = mn;
            const float p0 = __expf(sv[0][r] - mn);
            const float p1 = __expf(sv[1][r] - mn);
            sv[0][r] = p0; sv[1][r] = p1;
            li[r] = li[r] * al[r] + p0 + p1;   // own 2 cols; reduced after loop
        }
        if (l15 == 0) {
#pragma unroll
            for (int r = 0; r < 4; ++r) alphaS[w * 16 + q4 * 4 + r] = al[r];
        }
        // P -> LDS fp16, padded rows (stride 40 halves)
#pragma unroll
        for (int ms = 0; ms < 2; ++ms)
#pragma unroll
            for (int r = 0; r < 4; ++r) {
                const int row = w * 16 + q4 * 4 + r;
                Plds[row * PSTRIDE + ms * 16 + l15] = (_Float16)sv[ms][r];
            }
        ASYNC_BARRIER();   // P/alpha visible; K[t] reads retired

        // ---- O = O*alpha + P x U ----
#pragma unroll
        for (int is = 0; is < 4; ++is) {
            const float4 av = *(const float4*)&alphaS[is * 16 + q4 * 4];
            const v4f aa = {av.x, av.y, av.z, av.w};
#pragma unroll
            for (int js = 0; js < 4; ++js) O[is][js] *= aa;
        }
#pragma unroll
        for (int is = 0; is < 4; ++is) {
            const v8h Pf = *(const v8h*)(&Plds[(is * 16 + l15) * PSTRIDE + q4 * 8]);
#pragma unroll
            for (int js = 0; js < 4; ++js)
                O[is][js] = __builtin_amdgcn_mfma_f32_16x16x32_f16(Pf, Ur[js], O[is][js], 0, 0, 0);
        }
    }

    // drain wrap DMA before LDS could be reassigned at s_endpgm
    asm volatile("s_waitcnt vmcnt(0)" ::: "memory");

    // ---- epilogue: reduce li across the quad-row, write stats + raw O ----
#pragma unroll
    for (int r = 0; r < 4; ++r) li[r] = row_sum16(li[r]);
    if (l15 == 0) {
#pragma unroll
        for (int r = 0; r < 4; ++r) {
            const int n = nt * 64 + w * 16 + q4 * 4 + r;
            mstat[(size_t)(s * NB + b) * NS + n] = mi[r];
            lstat[(size_t)(s * NB + b) * NS + n] = li[r];
        }
    }
#pragma unroll
    for (int is = 0; is < 4; ++is)
#pragma unroll
        for (int js = 0; js < 4; ++js)
#pragma unroll
            for (int r = 0; r < 4; ++r) {
                _Float16* dst = Ppart + ((size_t)(s * NB + b) * NS + nt * 64 + is * 16
                                         + q4 * 4 + r) * NC + w * 64 + js * 16 + l15;
                __builtin_nontemporal_store((_Float16)O[is][js][r], dst);
            }
}

// ---------------- K3: merge 4 partials -> fp16 in-place (Ppart[0]) + GN sums
__global__ __launch_bounds__(256) void k_merge(_Float16* __restrict__ Pp,
    const float* __restrict__ mstat, const float* __restrict__ lstat,
    float* __restrict__ statacc)
{
    const int b = blockIdx.y, tid = threadIdx.x;
    const int n = blockIdx.x * 8 + (tid >> 5);
    const int c0 = (tid & 31) * 8;            // == group (tid&31) exactly
    const size_t nb = (size_t)b * NS + n;
    const size_t SP = (size_t)NB * NS;
    const float m0 = mstat[nb],          m1 = mstat[SP + nb];
    const float m2 = mstat[2 * SP + nb], m3 = mstat[3 * SP + nb];
    const float l0 = lstat[nb],          l1 = lstat[SP + nb];
    const float l2 = lstat[2 * SP + nb], l3 = lstat[3 * SP + nb];
    const float M  = fmaxf(fmaxf(m0, m1), fmaxf(m2, m3));
    const float e0 = __expf(m0 - M), e1 = __expf(m1 - M);
    const float e2 = __expf(m2 - M), e3 = __expf(m3 - M);
    const float inv = 1.f / (e0 * l0 + e1 * l1 + e2 * l2 + e3 * l3);
    const float w0 = e0 * inv, w1 = e1 * inv, w2 = e2 * inv, w3 = e3 * inv;
    const size_t base = nb * NC + c0;
    const v8h p0 = *(const v8h*)(Pp + base);
    const v8h p1 = *(const v8h*)(Pp + SP * NC + base);
    const v8h p2 = *(const v8h*)(Pp + 2 * SP * NC + base);
    const v8h p3 = *(const v8h*)(Pp + 3 * SP * NC + base);
    float s1 = 0.f, s2 = 0.f;
    v8h hm;
#pragma unroll
    for (int j = 0; j < 8; ++j) {
        const float v = w0 * (float)p0[j] + w1 * (float)p1[j]
                      + w2 * (float)p2[j] + w3 * (float)p3[j];
        s1 += v; s2 += v * v;
        hm[j] = (_Float16)v;
    }
    *(v8h*)(Pp + base) = hm;   // in-place merged (own element; race-free)

    __shared__ float r1[256], r2[256];
    r1[tid] = s1; r2[tid] = s2;
    __syncthreads();
    if (tid < 32) {
        float a = 0.f, q = 0.f;
#pragma unroll
        for (int k = 0; k < 8; ++k) { a += r1[tid + 32 * k]; q += r2[tid + 32 * k]; }
        atomicAdd(&statacc[(b * NG + tid) * 2 + 0], a);
        atomicAdd(&statacc[(b * NG + tid) * 2 + 1], q);
    }
}

// ---------------- K4: apply GN + residual, fp16 [b][n][c] -> fp32 [b][c][n] -
__global__ __launch_bounds__(256) void k_gnapply(const _Float16* __restrict__ Om,
    const float* __restrict__ Hand, const float* __restrict__ gnw,
    const float* __restrict__ gnb, const float* __restrict__ statacc,
    float* __restrict__ out)
{
    const int nt = blockIdx.x, ct = blockIdx.y, b = blockIdx.z;
    __shared__ float buf[64 * 65];
    const int tid = threadIdx.x;
    {
        const int nr = tid >> 4, c4 = (tid & 15) * 4;
#pragma unroll
        for (int k = 0; k < 4; ++k) {
            const int n = nr + 16 * k;
            const v4h v = *(const v4h*)(Om + ((size_t)b * NS + nt * 64 + n) * NC
                                        + ct * 64 + c4);
            buf[n * 65 + c4 + 0] = (float)v[0]; buf[n * 65 + c4 + 1] = (float)v[1];
            buf[n * 65 + c4 + 2] = (float)v[2]; buf[n * 65 + c4 + 3] = (float)v[3];
        }
    }
    __syncthreads();
    const int nw = tid & 63, c0 = tid >> 6;
#pragma unroll
    for (int k = 0; k < 16; ++k) {
        const int cl = c0 + 4 * k;
        const int c  = ct * 64 + cl;
        const int g  = c >> 3;
        const float s1   = statacc[(b * NG + g) * 2 + 0];
        const float s2   = statacc[(b * NG + g) * 2 + 1];
        const float mean = s1 * (1.f / 32768.f);
        const float var  = s2 * (1.f / 32768.f) - mean * mean;
        const float rstd = rsqrtf(var + GEPS);
        const size_t oidx = ((size_t)b * NC + c) * NS + nt * 64 + nw;
        out[oidx] = (buf[nw * 65 + cl] - mean) * rstd * gnw[c] + gnb[c] + Hand[oidx];
    }
}

extern "C" void kernel_launch(void* const* d_in, const int* in_sizes, int n_in,
                              void* d_out, int out_size, void* d_ws, size_t ws_size,
                              hipStream_t stream)
{
    const float* Hand = (const float*)d_in[0];
    const float* U    = (const float*)d_in[1];
    const float* WHw  = (const float*)d_in[2];
    const float* WHb  = (const float*)d_in[3];
    const float* WUw  = (const float*)d_in[4];
    const float* WUb  = (const float*)d_in[5];
    const float* gnw  = (const float*)d_in[6];
    const float* gnb  = (const float*)d_in[7];
    float* out = (float*)d_out;

    // workspace peak ~57.3 MiB (NSPLIT=4 Ppart = 32 MiB)
    char* ws = (char*)d_ws;
    _Float16* qT     = (_Float16*)(ws);                  //  8 MiB   [b][n][c]
    _Float16* kTsw   = (_Float16*)(ws + 8388608);        //  8.5 MiB padded 32-row tiles
    _Float16* Uh     = (_Float16*)(ws + 17301504);       //  8 MiB   [b][c][m]
    _Float16* Wh16   = (_Float16*)(ws + 25690112);       //  128 KiB (frag-order)
    _Float16* Wu16   = (_Float16*)(ws + 25821184);       //  128 KiB (frag-order)
    float*    mstat  = (float*)(ws + 25952256);          //  256 KiB [4][b][n]
    float*    lstat  = (float*)(ws + 26214400);          //  256 KiB
    float*    statacc= (float*)(ws + 26476544);          //  2 KiB [b][g][2]
    _Float16* Ppart  = (_Float16*)(ws + 26478592);       //  32 MiB [4][b][n][c]

    hipMemsetAsync(statacc, 0, NB * NG * 2 * sizeof(float), stream);
    k_convert<<<dim3((NC * NC) / 256), 256, 0, stream>>>(WHw, WUw, Wh16, Wu16);
    k_qkgemm <<<dim3(64, NB, 2), 256, 0, stream>>>(Hand, U, Wh16, Wu16, WHb, WUb, qT, kTsw, Uh);
    k_attn   <<<dim3(NB, 64, NSPLIT), 256, 0, stream>>>(qT, kTsw, Uh, Ppart, mstat, lstat);
    k_merge  <<<dim3(NS / 8, NB), 256, 0, stream>>>(Ppart, mstat, lstat, statacc);
    k_gnapply<<<dim3(64, 4, NB), 256, 0, stream>>>(Ppart, Hand, gnw, gnb, statacc, out);
}

// Round 8
// 278.604 us; speedup vs baseline: 1.3952x; 1.3952x over previous
//
#include <hip/hip_runtime.h>
#include <hip/hip_fp16.h>
#include <math.h>

// CrossFeatureAffinityPooling on gfx950 — R8
// R6 attn envelope (NSPLIT=3, bounds(256,3)) + SINGLE-barrier pipelined K-loop
// (P/alpha double-buffered, K DMA 2 tiles ahead, vmcnt(4) ledger) + conditional
// alpha-rescale skip. Merge is 3-way in-place fp16 (R7); gnapply reads fp16;
// qkgemm uses 128-thread blocks (1024 blocks) for gather latency hiding.

typedef _Float16 v8h __attribute__((ext_vector_type(8)));
typedef _Float16 v4h __attribute__((ext_vector_type(4)));
typedef float    v4f __attribute__((ext_vector_type(4)));

#define NB 4
#define NC 256
#define NS 4096
#define NG 32
#define GEPS 1e-5f
#define NSPLIT 3
#define KSTRIDE 272            // halves per K-tile row (256 data + 16 pad)
#define KTILE   8704           // halves per 32-row K tile (17408 B)
#define PSTRIDE 40             // halves per P row (32 data + 8 pad)

// raw barrier: LDS-visibility only (lgkm drain), vmem stays in flight
#define ASYNC_BARRIER() asm volatile("s_waitcnt lgkmcnt(0)\n\ts_barrier" ::: "memory")

// DPP rotation-reduce within each 16-lane row (the l15 domain of MFMA quads)
template <int CTRL>
__device__ __forceinline__ float dpp_rot(float x) {
    int r = __builtin_amdgcn_update_dpp(__float_as_int(x), __float_as_int(x),
                                        CTRL, 0xF, 0xF, false);
    return __int_as_float(r);
}
__device__ __forceinline__ float row_max16(float x) {
    x = fmaxf(x, dpp_rot<0x128>(x));
    x = fmaxf(x, dpp_rot<0x124>(x));
    x = fmaxf(x, dpp_rot<0x122>(x));
    x = fmaxf(x, dpp_rot<0x121>(x));
    return x;
}
__device__ __forceinline__ float row_sum16(float x) {
    x = x + dpp_rot<0x128>(x);
    x = x + dpp_rot<0x124>(x);
    x = x + dpp_rot<0x122>(x);
    x = x + dpp_rot<0x121>(x);
    return x;
}

// ---------------- K0: convert weights into MFMA-frag order (W only) --------
__global__ __launch_bounds__(256) void k_convert(const float* __restrict__ Wh,
    const float* __restrict__ Wu, _Float16* __restrict__ Wh16, _Float16* __restrict__ Wu16)
{
    const int i = blockIdx.x * 256 + threadIdx.x;   // i < NC*NC
    const int o = i >> 8, c = i & 255;
    const int idx = ((((o >> 4) * 8 + (c >> 5)) * 4 + ((c >> 3) & 3)) * 16
                     + (o & 15)) * 8 + (c & 7);
    Wh16[idx] = (_Float16)Wh[i];
    Wu16[idx] = (_Float16)Wu[i];
}

// ---------------- K1: q^T / k^T GEMM (+ fused Uh materialization) ----------
// 128-thread blocks (2 waves, 32-row tiles), 1024 blocks -> latency hiding for
// the strided A-gather without touching per-wave structure.
__global__ __launch_bounds__(128) void k_qkgemm(const float* __restrict__ Hand,
    const float* __restrict__ U, const _Float16* __restrict__ Wh16,
    const _Float16* __restrict__ Wu16, const float* __restrict__ WHb,
    const float* __restrict__ WUb, _Float16* __restrict__ qT,
    _Float16* __restrict__ kTsw, _Float16* __restrict__ Uh)
{
    const int nt = blockIdx.x, b = blockIdx.y, z = blockIdx.z;
    const float*    X    = z ? U    : Hand;
    const _Float16* W    = z ? Wu16 : Wh16;
    const float*    bias = z ? WUb  : WHb;

    const int tid = threadIdx.x, w = tid >> 6, lane = tid & 63;
    const int q4 = lane >> 4, l15 = lane & 15;
    const int n = nt * 32 + w * 16 + l15;

    const float* Xcol = X + (size_t)b * NC * NS + n;
    v8h A[8];
#pragma unroll
    for (int kc = 0; kc < 8; ++kc) {
        const int c0 = kc * 32 + q4 * 8;
        v8h a;
#pragma unroll
        for (int j = 0; j < 8; ++j) a[j] = (_Float16)Xcol[(size_t)(c0 + j) * NS];
        A[kc] = a;
    }

    // fused: z=1 blocks hold U^T[n][c] fp16 frags -> write Uh[b][c][n]
    if (z == 1) {
        _Float16* ub = Uh + (size_t)b * NC * NS + n;
#pragma unroll
        for (int kc = 0; kc < 8; ++kc) {
            const int c0 = kc * 32 + q4 * 8;
#pragma unroll
            for (int j = 0; j < 8; ++j) ub[(size_t)(c0 + j) * NS] = A[kc][j];
        }
    }

#pragma unroll 4
    for (int osub = 0; osub < 16; ++osub) {
        const int o = osub * 16 + l15;
        v4f acc = {0.f, 0.f, 0.f, 0.f};
#pragma unroll
        for (int kc = 0; kc < 8; ++kc) {
            const v8h bf = *(const v8h*)(W + ((size_t)(osub * 8 + kc) * 64 + lane) * 8);
            acc = __builtin_amdgcn_mfma_f32_16x16x32_f16(A[kc], bf, acc, 0, 0, 0);
        }
        const float bv = bias[o];
        if (z == 0) {
            _Float16* orow = qT + ((size_t)b * NS + nt * 32 + w * 16 + q4 * 4) * NC + o;
#pragma unroll
            for (int r = 0; r < 4; ++r) orow[(size_t)r * NC] = (_Float16)(acc[r] + bv);
        } else {
            _Float16* kb = kTsw + (size_t)b * 128 * KTILE;
#pragma unroll
            for (int r = 0; r < 4; ++r) {
                const int m = nt * 32 + w * 16 + q4 * 4 + r;
                kb[(size_t)(m >> 5) * KTILE + (m & 31) * KSTRIDE + o] = (_Float16)(acc[r] + bv);
            }
        }
    }
}

// ---------------- K2: flash attention partial — single-barrier pipeline ----
// Per-wave VMEM ledger (steady state), queue oldest->newest at the vmcnt:
//   [DMA K(t+1) x5 (issued post-barrier of iter t-1), U(t) x4 (iter-t top)]
// -> s_waitcnt vmcnt(4) retires exactly DMA(t+1). PV's compiler-inserted wait
// on Ur retires U(t). DMA K(t+2) (post-barrier) reuses buffer (t&1), whose
// tile K(t) was fully consumed by all waves pre-barrier. P/alpha double-buffered
// so PV(t) [post-barrier] never races the next P-write [pre-next-barrier].
__global__ __launch_bounds__(256, 3) void k_attn(const _Float16* __restrict__ qT,
    const _Float16* __restrict__ kTsw, const _Float16* __restrict__ Uh,
    _Float16* __restrict__ Ppart, float* __restrict__ mstat, float* __restrict__ lstat)
{
    const int b  = blockIdx.x;
    const int nt = blockIdx.y;
    const int s  = blockIdx.z;
    const int t0 = (s == 0) ? 0 : (s == 1 ? 43 : 86);
    const int t1 = (s == 2) ? 128 : t0 + 43;

    __shared__ __align__(16) _Float16 Klds[2][KTILE];       // 2 x 17 KiB
    __shared__ __align__(16) _Float16 Plds[2][64 * PSTRIDE];// 2 x 5 KiB
    __shared__ __align__(16) float alphaS[2][64];           // 2 x 256 B

    const int tid = threadIdx.x, w = tid >> 6, lane = tid & 63;
    const int q4 = lane >> 4, l15 = lane & 15;

    const _Float16* kTb = kTsw + (size_t)b * 128 * KTILE;
    const _Float16* Uhb = Uh + (size_t)b * NC * NS;

    // ---- prologue: Q first (clean ledger), then K(t0), then K(t0+1) ----
    v8h Q[8];
    {
        const _Float16* qrow = qT + ((size_t)b * NS + nt * 64 + w * 16 + l15) * NC;
#pragma unroll
        for (int kc = 0; kc < 8; ++kc) Q[kc] = *(const v8h*)(qrow + kc * 32 + q4 * 8);
    }
    asm volatile("s_waitcnt vmcnt(0)" ::: "memory");   // Q resident, ledger empty
    {
        const _Float16* src = kTb + (size_t)t0 * KTILE;
#pragma unroll
        for (int j = 0; j < 5; ++j) {
            const int ch = (w * 5 + j) % 17;
            __builtin_amdgcn_global_load_lds(
                (const __attribute__((address_space(1))) void*)(src + ch * 512 + lane * 8),
                (__attribute__((address_space(3))) void*)(&Klds[t0 & 1][ch * 512]), 16, 0, 0);
        }
    }
    asm volatile("s_waitcnt vmcnt(0)" ::: "memory");   // own K(t0) chunks landed
    ASYNC_BARRIER();                                   // all waves' K(t0) resident
    {
        const _Float16* src = kTb + (size_t)(t0 + 1) * KTILE;
#pragma unroll
        for (int j = 0; j < 5; ++j) {
            const int ch = (w * 5 + j) % 17;
            __builtin_amdgcn_global_load_lds(
                (const __attribute__((address_space(1))) void*)(src + ch * 512 + lane * 8),
                (__attribute__((address_space(3))) void*)(&Klds[(t0 + 1) & 1][ch * 512]), 16, 0, 0);
        }
    }
    // ledger entering loop: [DMA(t0+1) x5]

    v4f O[4][4];
#pragma unroll
    for (int i = 0; i < 4; ++i)
#pragma unroll
        for (int j = 0; j < 4; ++j) O[i][j] = (v4f){0.f, 0.f, 0.f, 0.f};
    float mi[4] = {-INFINITY, -INFINITY, -INFINITY, -INFINITY};
    float li[4] = {0.f, 0.f, 0.f, 0.f};   // lane-local partial (own cols only)

    for (int t = t0; t < t1; ++t) {
        const int p = t & 1;
        const int m0 = t * 32;

        // ---- U(t) -> VGPRs (hidden behind QK+softmax; used in PV below) ----
        v8h Ur[4];
#pragma unroll
        for (int js = 0; js < 4; ++js)
            Ur[js] = *(const v8h*)(Uhb + (size_t)(w * 64 + js * 16 + l15) * NS + m0 + q4 * 8);

        // ---- QK^T: 16 n-rows x 32 m per wave, from Klds[p] ----
        v4f sv[2];
        sv[0] = (v4f){0.f, 0.f, 0.f, 0.f};
        sv[1] = (v4f){0.f, 0.f, 0.f, 0.f};
#pragma unroll
        for (int kc = 0; kc < 8; ++kc) {
#pragma unroll
            for (int ms = 0; ms < 2; ++ms) {
                const v8h kf = *(const v8h*)(&Klds[p][(ms * 16 + l15) * KSTRIDE
                                             + (kc * 4 + q4) * 8]);
                sv[ms] = __builtin_amdgcn_mfma_f32_16x16x32_f16(Q[kc], kf, sv[ms], 0, 0, 0);
            }
        }

        // ---- online softmax: DPP max, lane-local li ----
        float al[4];
#pragma unroll
        for (int r = 0; r < 4; ++r) {
            const float tm = row_max16(fmaxf(sv[0][r], sv[1][r]));
            const float mn = fmaxf(mi[r], tm);
            al[r] = __expf(mi[r] - mn);
            mi[r] = mn;
            const float p0 = __expf(sv[0][r] - mn);
            const float p1 = __expf(sv[1][r] - mn);
            sv[0][r] = p0; sv[1][r] = p1;
            li[r] = li[r] * al[r] + p0 + p1;   // own 2 cols; reduced after loop
        }
        if (l15 == 0) {
#pragma unroll
            for (int r = 0; r < 4; ++r) alphaS[p][w * 16 + q4 * 4 + r] = al[r];
        }
        // P -> Plds[p], padded rows (stride 40 halves)
#pragma unroll
        for (int ms = 0; ms < 2; ++ms)
#pragma unroll
            for (int r = 0; r < 4; ++r) {
                const int row = w * 16 + q4 * 4 + r;
                Plds[p][row * PSTRIDE + ms * 16 + l15] = (_Float16)sv[ms][r];
            }

        // ---- the ONE barrier: K(t+1) resident everywhere + P/alpha handoff ----
        asm volatile("s_waitcnt vmcnt(4)" ::: "memory");  // retire DMA(t+1), keep U(t)
        ASYNC_BARRIER();

        // ---- DMA K(t+2) into Klds[p] (K(t) consumed by all pre-barrier) ----
        {
            const int tn = (t + 2 < t1) ? t + 2 : t0;   // wrap: uniform counts
            const _Float16* src = kTb + (size_t)tn * KTILE;
#pragma unroll
            for (int j = 0; j < 5; ++j) {
                const int ch = (w * 5 + j) % 17;
                __builtin_amdgcn_global_load_lds(
                    (const __attribute__((address_space(1))) void*)(src + ch * 512 + lane * 8),
                    (__attribute__((address_space(3))) void*)(&Klds[p][ch * 512]), 16, 0, 0);
            }
        }

        // ---- conditional O-rescale (skip when every alpha == 1.0) ----
        float4 av[4];
#pragma unroll
        for (int is = 0; is < 4; ++is)
            av[is] = *(const float4*)&alphaS[p][is * 16 + q4 * 4];
        bool need = false;
#pragma unroll
        for (int is = 0; is < 4; ++is)
            need |= (av[is].x < 1.f) | (av[is].y < 1.f) | (av[is].z < 1.f) | (av[is].w < 1.f);
        if (__ballot(need)) {
#pragma unroll
            for (int is = 0; is < 4; ++is) {
                const v4f aa = {av[is].x, av[is].y, av[is].z, av[is].w};
#pragma unroll
                for (int js = 0; js < 4; ++js) O[is][js] *= aa;
            }
        }

        // ---- O += P x U  (P from Plds[p], U from regs) ----
#pragma unroll
        for (int is = 0; is < 4; ++is) {
            const v8h Pf = *(const v8h*)(&Plds[p][(is * 16 + l15) * PSTRIDE + q4 * 8]);
#pragma unroll
            for (int js = 0; js < 4; ++js)
                O[is][js] = __builtin_amdgcn_mfma_f32_16x16x32_f16(Pf, Ur[js], O[is][js], 0, 0, 0);
        }
    }

    // drain wrap DMA before LDS could be reassigned at s_endpgm
    asm volatile("s_waitcnt vmcnt(0)" ::: "memory");

    // ---- epilogue: reduce li across the quad-row, write stats + raw O ----
#pragma unroll
    for (int r = 0; r < 4; ++r) li[r] = row_sum16(li[r]);
    if (l15 == 0) {
#pragma unroll
        for (int r = 0; r < 4; ++r) {
            const int n = nt * 64 + w * 16 + q4 * 4 + r;
            mstat[(size_t)(s * NB + b) * NS + n] = mi[r];
            lstat[(size_t)(s * NB + b) * NS + n] = li[r];
        }
    }
#pragma unroll
    for (int is = 0; is < 4; ++is)
#pragma unroll
        for (int js = 0; js < 4; ++js)
#pragma unroll
            for (int r = 0; r < 4; ++r) {
                _Float16* dst = Ppart + ((size_t)(s * NB + b) * NS + nt * 64 + is * 16
                                         + q4 * 4 + r) * NC + w * 64 + js * 16 + l15;
                __builtin_nontemporal_store((_Float16)O[is][js][r], dst);
            }
}

// ---------------- K3: merge 3 partials -> fp16 in-place (Ppart[0]) + GN sums
__global__ __launch_bounds__(256) void k_merge(_Float16* __restrict__ Pp,
    const float* __restrict__ mstat, const float* __restrict__ lstat,
    float* __restrict__ statacc)
{
    const int b = blockIdx.y, tid = threadIdx.x;
    const int n = blockIdx.x * 8 + (tid >> 5);
    const int c0 = (tid & 31) * 8;            // == group (tid&31) exactly
    const size_t nb = (size_t)b * NS + n;
    const size_t SP = (size_t)NB * NS;
    const float m0 = mstat[nb], m1 = mstat[SP + nb], m2 = mstat[2 * SP + nb];
    const float l0 = lstat[nb], l1 = lstat[SP + nb], l2 = lstat[2 * SP + nb];
    const float M  = fmaxf(m0, fmaxf(m1, m2));
    const float e0 = __expf(m0 - M), e1 = __expf(m1 - M), e2 = __expf(m2 - M);
    const float inv = 1.f / (e0 * l0 + e1 * l1 + e2 * l2);
    const float w0 = e0 * inv, w1 = e1 * inv, w2 = e2 * inv;
    const size_t base = nb * NC + c0;
    const v8h p0 = *(const v8h*)(Pp + base);
    const v8h p1 = *(const v8h*)(Pp + SP * NC + base);
    const v8h p2 = *(const v8h*)(Pp + 2 * SP * NC + base);
    float s1 = 0.f, s2 = 0.f;
    v8h hm;
#pragma unroll
    for (int j = 0; j < 8; ++j) {
        const float v = w0 * (float)p0[j] + w1 * (float)p1[j] + w2 * (float)p2[j];
        s1 += v; s2 += v * v;
        hm[j] = (_Float16)v;
    }
    *(v8h*)(Pp + base) = hm;   // in-place merged (own element; race-free)

    __shared__ float r1[256], r2[256];
    r1[tid] = s1; r2[tid] = s2;
    __syncthreads();
    if (tid < 32) {
        float a = 0.f, q = 0.f;
#pragma unroll
        for (int k = 0; k < 8; ++k) { a += r1[tid + 32 * k]; q += r2[tid + 32 * k]; }
        atomicAdd(&statacc[(b * NG + tid) * 2 + 0], a);
        atomicAdd(&statacc[(b * NG + tid) * 2 + 1], q);
    }
}

// ---------------- K4: apply GN + residual, fp16 [b][n][c] -> fp32 [b][c][n] -
__global__ __launch_bounds__(256) void k_gnapply(const _Float16* __restrict__ Om,
    const float* __restrict__ Hand, const float* __restrict__ gnw,
    const float* __restrict__ gnb, const float* __restrict__ statacc,
    float* __restrict__ out)
{
    const int nt = blockIdx.x, ct = blockIdx.y, b = blockIdx.z;
    __shared__ float buf[64 * 65];
    const int tid = threadIdx.x;
    {
        const int nr = tid >> 4, c4 = (tid & 15) * 4;
#pragma unroll
        for (int k = 0; k < 4; ++k) {
            const int n = nr + 16 * k;
            const v4h v = *(const v4h*)(Om + ((size_t)b * NS + nt * 64 + n) * NC
                                        + ct * 64 + c4);
            buf[n * 65 + c4 + 0] = (float)v[0]; buf[n * 65 + c4 + 1] = (float)v[1];
            buf[n * 65 + c4 + 2] = (float)v[2]; buf[n * 65 + c4 + 3] = (float)v[3];
        }
    }
    __syncthreads();
    const int nw = tid & 63, c0 = tid >> 6;
#pragma unroll
    for (int k = 0; k < 16; ++k) {
        const int cl = c0 + 4 * k;
        const int c  = ct * 64 + cl;
        const int g  = c >> 3;
        const float s1   = statacc[(b * NG + g) * 2 + 0];
        const float s2   = statacc[(b * NG + g) * 2 + 1];
        const float mean = s1 * (1.f / 32768.f);
        const float var  = s2 * (1.f / 32768.f) - mean * mean;
        const float rstd = rsqrtf(var + GEPS);
        const size_t oidx = ((size_t)b * NC + c) * NS + nt * 64 + nw;
        out[oidx] = (buf[nw * 65 + cl] - mean) * rstd * gnw[c] + gnb[c] + Hand[oidx];
    }
}

extern "C" void kernel_launch(void* const* d_in, const int* in_sizes, int n_in,
                              void* d_out, int out_size, void* d_ws, size_t ws_size,
                              hipStream_t stream)
{
    const float* Hand = (const float*)d_in[0];
    const float* U    = (const float*)d_in[1];
    const float* WHw  = (const float*)d_in[2];
    const float* WHb  = (const float*)d_in[3];
    const float* WUw  = (const float*)d_in[4];
    const float* WUb  = (const float*)d_in[5];
    const float* gnw  = (const float*)d_in[6];
    const float* gnb  = (const float*)d_in[7];
    float* out = (float*)d_out;

    // workspace ~49.2 MiB (same envelope as R6, known to fit)
    char* ws = (char*)d_ws;
    _Float16* qT     = (_Float16*)(ws);                  //  8 MiB   [b][n][c]
    _Float16* kTsw   = (_Float16*)(ws + 8388608);        //  8.5 MiB padded 32-row tiles
    _Float16* Uh     = (_Float16*)(ws + 17301504);       //  8 MiB   [b][c][m]
    _Float16* Wh16   = (_Float16*)(ws + 25690112);       //  128 KiB (frag-order)
    _Float16* Wu16   = (_Float16*)(ws + 25821184);       //  128 KiB (frag-order)
    float*    mstat  = (float*)(ws + 25952256);          //  192 KiB [3][b][n]
    float*    lstat  = (float*)(ws + 26148864);          //  192 KiB
    float*    statacc= (float*)(ws + 26345472);          //  2 KiB [b][g][2]
    _Float16* Ppart  = (_Float16*)(ws + 26347520);       //  24 MiB [3][b][n][c]

    hipMemsetAsync(statacc, 0, NB * NG * 2 * sizeof(float), stream);
    k_convert<<<dim3((NC * NC) / 256), 256, 0, stream>>>(WHw, WUw, Wh16, Wu16);
    k_qkgemm <<<dim3(128, NB, 2), 128, 0, stream>>>(Hand, U, Wh16, Wu16, WHb, WUb, qT, kTsw, Uh);
    k_attn   <<<dim3(NB, 64, NSPLIT), 256, 0, stream>>>(qT, kTsw, Uh, Ppart, mstat, lstat);
    k_merge  <<<dim3(NS / 8, NB), 256, 0, stream>>>(Ppart, mstat, lstat, statacc);
    k_gnapply<<<dim3(64, 4, NB), 256, 0, stream>>>(Ppart, Hand, gnw, gnb, statacc, out);
}